// Round 6
// baseline (25.556 us; speedup 1.0000x reference)
//
#include <hip/hip_runtime.h>
#include <math.h>

typedef float v2f __attribute__((ext_vector_type(2)));

// Guaranteed packed fp32 FMA (VOP3P v_pk_fma_f32, gfx90a+/gfx950).
static __device__ __forceinline__ v2f pkfma(v2f a, v2f b, v2f c) {
    v2f d;
    asm("v_pk_fma_f32 %0, %1, %2, %3" : "=v"(d) : "v"(a), "v"(b), "v"(c));
    return d;
}

#define NBATCH 8
#define PTOT   4096
#define NG     2048              // points per group
#define S      32                // ref slices per problem
#define SLEN   (NG / S)          // 64 refs per slice
#define QPT    16                // queries per thread (consecutive)
#define NT     256               // threads per block (2 slices per block)
#define NPROB  32                // 8 batches x 2 groups x 2 directions
#define NBLK1  (NPROB * S / 2)   // 512 blocks, pass 1
#define NPART  (NPROB * S * NG)  // 2M floats (8 MB)

// Pass 1: one block = (problem, slice-pair). Half-block (128 thr) per slice.
// Each thread owns 16 consecutive queries; refs staged as SoA-of-float4 so the
// inner loop is packed fp32: per 4 refs x query = 6 v_pk_fma_f32 + 2 min3
// = 2.0 VALU instr/pair. Each broadcast ds_read feeds 16 queries.
__global__ __launch_bounds__(256, 2) void chamfer_pass1(
    const float* __restrict__ x, const float* __restrict__ y,
    float* __restrict__ pmin)
{
    __shared__ float  raw[2 * SLEN * 3];   // 128 refs x 3 = 1.5 KiB
    __shared__ float4 refX[2 * SLEN / 4];  // 32 groups of 4 refs
    __shared__ float4 refY[2 * SLEN / 4];
    __shared__ float4 refZ[2 * SLEN / 4];
    __shared__ float4 refW[2 * SLEN / 4];  // |r|^2

    const int blk   = blockIdx.x;
    const int tid   = threadIdx.x;
    const int prob  = blk >> 4;              // 0..31
    const int spair = blk & 15;              // slice pair 0..15
    const int dir   = prob >> 4;             // 0: x->y, 1: y->x
    const int bg    = prob & 15;
    const int b     = bg >> 1;               // batch
    const int g     = bg & 1;                // group

    const float* qb = (dir == 0 ? x : y) + (size_t)(b * PTOT + g * NG) * 3;
    const float* rb = (dir == 0 ? y : x) + (size_t)(b * PTOT + g * NG) * 3;

    // Stage 128 refs (2 slices, contiguous): 384 floats = 96 float4.
    if (tid < 96) {
        float4 v = ((const float4*)(rb + spair * 384))[tid];
        ((float4*)raw)[tid] = v;
    }

    // Query loads hoisted above the barrier: 16 q x 3 = 48 floats = 12 float4.
    const int half = tid >> 7;        // which slice of the pair
    const int t    = tid & 127;       // thread-in-half
    float4 qv[12];
    {
        const float4* qp = (const float4*)qb + (size_t)t * 12;
        #pragma unroll
        for (int i = 0; i < 12; i++) qv[i] = qp[i];
    }

    __syncthreads();

    // Transpose to SoA-of-float4 (32 threads, one 4-ref group each).
    if (tid < 32) {
        const float* p = raw + tid * 12;
        float x0 = p[0], y0 = p[1],  z0 = p[2];
        float x1 = p[3], y1 = p[4],  z1 = p[5];
        float x2 = p[6], y2 = p[7],  z2 = p[8];
        float x3 = p[9], y3 = p[10], z3 = p[11];
        refX[tid] = make_float4(x0, x1, x2, x3);
        refY[tid] = make_float4(y0, y1, y2, y3);
        refZ[tid] = make_float4(z0, z1, z2, z3);
        refW[tid] = make_float4(fmaf(x0, x0, fmaf(y0, y0, z0 * z0)),
                                fmaf(x1, x1, fmaf(y1, y1, z1 * z1)),
                                fmaf(x2, x2, fmaf(y2, y2, z2 * z2)),
                                fmaf(x3, x3, fmaf(y3, y3, z3 * z3)));
    }

    // Build duplicated packed coefficients while LDS settles.
    v2f axd[QPT], ayd[QPT], azd[QPT];
    float qn[QPT], mn[QPT];
    const float* qf = reinterpret_cast<const float*>(qv);
    #pragma unroll
    for (int k = 0; k < QPT; k++) {
        float qx = qf[k * 3 + 0];
        float qy = qf[k * 3 + 1];
        float qz = qf[k * 3 + 2];
        float ax = -2.0f * qx, ay = -2.0f * qy, az = -2.0f * qz;
        axd[k] = (v2f){ax, ax};
        ayd[k] = (v2f){ay, ay};
        azd[k] = (v2f){az, az};
        qn[k] = fmaf(qx, qx, fmaf(qy, qy, qz * qz));
        mn[k] = 3.4e38f;
    }

    __syncthreads();

    // 16 groups of 4 refs for this half's slice. Per group: 4 broadcast
    // ds_read_b128 + 16 q x (6 pk_fma + 2 min3) = 128 VALU instr.
    const int g0 = half * (SLEN / 4);
    #pragma unroll 2
    for (int gi = 0; gi < SLEN / 4; gi++) {
        const int n4 = g0 + gi;
        float4 X = refX[n4], Y = refY[n4], Z = refZ[n4], W = refW[n4];
        v2f X01 = (v2f){X.x, X.y}, X23 = (v2f){X.z, X.w};
        v2f Y01 = (v2f){Y.x, Y.y}, Y23 = (v2f){Y.z, Y.w};
        v2f Z01 = (v2f){Z.x, Z.y}, Z23 = (v2f){Z.z, Z.w};
        v2f W01 = (v2f){W.x, W.y}, W23 = (v2f){W.z, W.w};
        #pragma unroll
        for (int k = 0; k < QPT; k++) {
            v2f t01 = pkfma(X01, axd[k], W01);
            t01     = pkfma(Y01, ayd[k], t01);
            t01     = pkfma(Z01, azd[k], t01);
            v2f t23 = pkfma(X23, axd[k], W23);
            t23     = pkfma(Y23, ayd[k], t23);
            t23     = pkfma(Z23, azd[k], t23);
            mn[k] = fminf(fminf(t01.x, t01.y), mn[k]);   // -> v_min3_f32
            mn[k] = fminf(fminf(t23.x, t23.y), mn[k]);   // -> v_min3_f32
        }
    }

    // 16 contiguous floats per thread -> 4x global_store_dwordx4.
    const int slice = spair * 2 + half;
    float* op = pmin + (size_t)(prob * S + slice) * NG + t * QPT;
    #pragma unroll
    for (int i = 0; i < 4; i++) {
        ((float4*)op)[i] = make_float4(mn[4*i+0] + qn[4*i+0],
                                       mn[4*i+1] + qn[4*i+1],
                                       mn[4*i+2] + qn[4*i+2],
                                       mn[4*i+3] + qn[4*i+3]);
    }
}

// Pass 2: per (problem, query) min over the 32 slices, sqrt, block-sum.
__global__ __launch_bounds__(256) void chamfer_pass2(
    const float* __restrict__ pmin, float* __restrict__ bsum)
{
    __shared__ float s4[4];
    const int gid  = blockIdx.x * 256 + threadIdx.x;   // 0..65535
    const int prob = gid >> 11;                        // /2048
    const int q    = gid & (NG - 1);

    float m0 = 3.4e38f, m1 = 3.4e38f;
    #pragma unroll
    for (int s = 0; s < S; s += 2) {
        m0 = fminf(m0, pmin[(size_t)(prob * S + s) * NG + q]);
        m1 = fminf(m1, pmin[(size_t)(prob * S + s + 1) * NG + q]);
    }
    float m = fminf(m0, m1);

    float d = sqrtf(fmaxf(m, 0.0f));   // guard cancellation

    for (int off = 32; off > 0; off >>= 1)
        d += __shfl_down(d, off, 64);
    if ((threadIdx.x & 63) == 0) s4[threadIdx.x >> 6] = d;
    __syncthreads();
    if (threadIdx.x == 0)
        bsum[blockIdx.x] = (s4[0] + s4[1]) + (s4[2] + s4[3]);
}

// Pass 3: deterministic reduction of the 256 block sums.
__global__ __launch_bounds__(256) void chamfer_pass3(
    const float* __restrict__ bsum, float* __restrict__ out)
{
    __shared__ float s4[4];
    const int tid = threadIdx.x;
    float v = bsum[tid];
    for (int off = 32; off > 0; off >>= 1)
        v += __shfl_down(v, off, 64);
    if ((tid & 63) == 0) s4[tid >> 6] = v;
    __syncthreads();
    if (tid == 0)
        out[0] = ((s4[0] + s4[1]) + (s4[2] + s4[3])) * (1.0f / 16384.0f);
}

extern "C" void kernel_launch(void* const* d_in, const int* in_sizes, int n_in,
                              void* d_out, int out_size, void* d_ws, size_t ws_size,
                              hipStream_t stream) {
    const float* x = (const float*)d_in[0];
    const float* y = (const float*)d_in[1];
    float* out  = (float*)d_out;
    float* pmin = (float*)d_ws;                 // 2M floats (8 MB)
    float* bsum = pmin + NPART;                 // 256 floats

    chamfer_pass1<<<NBLK1, NT, 0, stream>>>(x, y, pmin);
    chamfer_pass2<<<256, NT, 0, stream>>>(pmin, bsum);
    chamfer_pass3<<<1, NT, 0, stream>>>(bsum, out);
}